// Round 1
// baseline (325.558 us; speedup 1.0000x reference)
//
#include <hip/hip_runtime.h>

typedef unsigned short ushort_t;
typedef __bf16 bf16x8 __attribute__((ext_vector_type(8)));
typedef float f32x4 __attribute__((ext_vector_type(4)));

__device__ __forceinline__ unsigned short f2bf(float f) {
    unsigned u = __float_as_uint(f);
    u += 0x7fffu + ((u >> 16) & 1u);
    return (unsigned short)(u >> 16);
}
__device__ __forceinline__ float bf2f(unsigned short h) {
    return __uint_as_float(((unsigned)h) << 16);
}
__device__ __forceinline__ float gelu_f(float x) {
    return 0.5f * x * (1.0f + erff(x * 0.70710678118654752440f));
}

// ---------------- prep: convert X -> bf16 AND transpose both weights ----------------
// blocks [0,16384): X rows; [16384,18432): W_down transpose; [18432,19456): W_row transpose
__global__ void prep_kernel(const float4* __restrict__ former,
                            const float4* __restrict__ hidden,
                            uint4* __restrict__ Xb4,
                            const float* __restrict__ Wd, ushort_t* __restrict__ WdT,
                            const float* __restrict__ Wr, ushort_t* __restrict__ WrT)
{
    const int blk = blockIdx.x;
    const int tid = threadIdx.x;
    if (blk < 16384) {
        const int row = blk;
        const float4* src = (tid < 128)
            ? (former + (size_t)row * 256 + (tid & 127) * 2)
            : (hidden + (size_t)row * 256 + (tid & 127) * 2);
        float4 a = src[0], b = src[1];
        uint4 o;
        o.x = f2bf(a.x) | ((unsigned)f2bf(a.y) << 16);
        o.y = f2bf(a.z) | ((unsigned)f2bf(a.w) << 16);
        o.z = f2bf(b.x) | ((unsigned)f2bf(b.y) << 16);
        o.w = f2bf(b.z) | ((unsigned)f2bf(b.w) << 16);
        Xb4[(size_t)row * 256 + tid] = o;
    } else {
        __shared__ float tile[32][33];
        const float* W; ushort_t* Wt; int R, C, b;
        if (blk < 16384 + 2048) { b = blk - 16384; W = Wd; Wt = WdT; R = 2048; C = 1024; }
        else                    { b = blk - 18432; W = Wr; Wt = WrT; R = 1024; C = 1024; }
        const int bx = (b & 31) * 32;
        const int by = (b >> 5) * 32;
        const int tx = tid & 31, ty = tid >> 5;
        #pragma unroll
        for (int j = 0; j < 32; j += 8)
            tile[ty + j][tx] = W[(size_t)(by + ty + j) * C + bx + tx];
        __syncthreads();
        #pragma unroll
        for (int j = 0; j < 32; j += 8)
            Wt[(size_t)(bx + ty + j) * R + by + tx] = f2bf(tile[tx][ty + j]);
    }
}

// ---------------- 128^2 m97-style GEMM (kept for GEMM2: small M, needs block count) ----
template <bool OUT_BF16>
__global__ void gemm_bias_gelu_kernel(const ushort_t* __restrict__ A,
                                      const ushort_t* __restrict__ Bt,
                                      const float* __restrict__ bias,
                                      void* __restrict__ C,
                                      int M, int N, int K)
{
    __shared__ __align__(16) ushort_t sA[128 * 64];
    __shared__ __align__(16) ushort_t sB[128 * 64];
    const int tid  = threadIdx.x;
    const int lane = tid & 63;
    const int wave = tid >> 6;
    const int wm = (wave & 1) * 64;
    const int wn = (wave >> 1) * 64;
    const long bm = (long)blockIdx.x * 128;
    const long bn = (long)blockIdx.y * 128;

    f32x4 acc[4][4] = {};

    const int srow = wave * 8 + (lane >> 3);
    const int scol = ((lane & 7) ^ (lane >> 3)) * 8;
    const int ldsbase = wave * 512;

    for (int k0 = 0; k0 < K; k0 += 64) {
        __syncthreads();
        #pragma unroll
        for (int it = 0; it < 4; ++it) {
            const ushort_t* gA = A + (size_t)(bm + it * 32 + srow) * K + k0 + scol;
            const ushort_t* gB = Bt + (size_t)(bn + it * 32 + srow) * K + k0 + scol;
            __builtin_amdgcn_global_load_lds(
                (__attribute__((address_space(1))) void*)gA,
                (__attribute__((address_space(3))) void*)&sA[ldsbase + it * 2048], 16, 0, 0);
            __builtin_amdgcn_global_load_lds(
                (__attribute__((address_space(1))) void*)gB,
                (__attribute__((address_space(3))) void*)&sB[ldsbase + it * 2048], 16, 0, 0);
        }
        __syncthreads();

        const int arow = wm + (lane & 15);
        const int brow = wn + (lane & 15);
        const int sw = lane & 7;
        const int cbase = lane >> 4;
        #pragma unroll
        for (int kk = 0; kk < 64; kk += 32) {
            const int koff = (((kk >> 3) + cbase) ^ sw) << 3;
            bf16x8 af[4], bfr[4];
            #pragma unroll
            for (int t = 0; t < 4; ++t) {
                af[t]  = *(const bf16x8*)&sA[(arow + t * 16) * 64 + koff];
                bfr[t] = *(const bf16x8*)&sB[(brow + t * 16) * 64 + koff];
            }
            #pragma unroll
            for (int i = 0; i < 4; ++i)
                #pragma unroll
                for (int j = 0; j < 4; ++j)
                    acc[i][j] = __builtin_amdgcn_mfma_f32_16x16x32_bf16(af[i], bfr[j], acc[i][j], 0, 0, 0);
        }
    }

    #pragma unroll
    for (int i = 0; i < 4; ++i) {
        const long row0 = bm + wm + i * 16 + (lane >> 4) * 4;
        #pragma unroll
        for (int j = 0; j < 4; ++j) {
            const long col = bn + wn + j * 16 + (lane & 15);
            const float bv = bias[col];
            #pragma unroll
            for (int r = 0; r < 4; ++r) {
                float v = gelu_f(acc[i][j][r] + bv);
                if (OUT_BF16)
                    ((ushort_t*)C)[(size_t)(row0 + r) * N + col] = f2bf(v);
                else
                    ((float*)C)[(size_t)(row0 + r) * N + col] = v;
            }
        }
    }
}

// ---------------- 256^2 8-wave deep-pipelined GEMM (GEMM1) --------------------------
// Counted-vmcnt schedule (T3+T4), slot-level double buffer via quadrant-death staging,
// setprio around MFMA clusters (T5), same XOR chunk swizzle as the 128^2 kernel (T2).
//
// LDS (dynamic, 128 KiB): sA[2 buf][2 mh][128][64] bf16, sB[2 buf][2 nh][128][64].
//   A slot mh: rows {wrb*128 + mh*64 + r6}, physical hr = wrb*64 + r6.
//   B slot nh: rows {wcb*64  + nh*32 + r5}, physical hr = wcb*32 + r5.
// Quadrant order per tile: q=(mh,nh) = (0,0),(0,1),(1,0),(1,1).
//   A-mh0 dead after q1 -> restaged (tile t+2) at q2; B-nh0 dead after q2 -> q3;
//   A-mh1/B-nh1 restaged (tile t+1) at next tile's q0/q1 (other buffer).
// Ledger (2 load-instrs per stage, per wave): at q0 outstanding = 12, vmcnt(8)
//   completes exactly A-mh0(t)+B-nh0(t); at q1 outstanding = 10, vmcnt(6) completes
//   A-mh1(t)+B-nh1(t); q2/q3 need no wait. Last tile: vmcnt(0) once at q0.
template <bool OUT_BF16>
__global__ __launch_bounds__(512, 2)
void gemm256_bias_gelu_kernel(const ushort_t* __restrict__ A,
                              const ushort_t* __restrict__ Bt,
                              const float* __restrict__ bias,
                              void* __restrict__ C,
                              int M, int N, int K)
{
    extern __shared__ float4 smem4[];
    ushort_t* sA = (ushort_t*)smem4;   // 2*2*128*64 = 32768 elements (64 KiB)
    ushort_t* sB = sA + 32768;         // 64 KiB

    const int tid  = threadIdx.x;
    const int lane = tid & 63;
    const int w    = tid >> 6;          // 0..7
    const int wr   = w >> 2;            // 0..1  A row-block of this wave
    const int wcq  = w & 3;             // 0..3  B col-block of this wave
    const long bm = (long)blockIdx.x * 256;
    const long bn = (long)blockIdx.y * 256;
    const int NT = K >> 6;              // K-tiles of 64 (even; GEMM1: 32)

    // staging: per stage call each thread issues 2 x global_load_lds(16B).
    // LDS dest is wave-uniform base + lane*16 (hr = j*64 + w*8 + (lane>>3),
    // chunk lane&7); global source chunk pre-swizzled by (lane>>3) = hr&7.
    const int srow = w * 8 + (lane >> 3);             // 0..63
    const int scol = ((lane & 7) ^ (lane >> 3)) * 8;  // swizzled global k-chunk (elems)
    const int sdst = (lane & 7) * 8;                  // lds chunk (elems)

    const int l15 = lane & 15;
    const int lg  = lane >> 4;
    const int sw  = lane & 7;
    const int ck[2] = { ((0 + lg) ^ sw) * 8, ((4 + lg) ^ sw) * 8 };

    f32x4 acc[8][4] = {};

    auto stageA = [&](int t_, int mh_, int buf_) {
        #pragma unroll
        for (int j = 0; j < 2; ++j) {
            const ushort_t* g = A + (size_t)(bm + j * 128 + mh_ * 64 + srow) * K
                                  + t_ * 64 + scol;
            ushort_t* d = sA + buf_ * 16384 + mh_ * 8192 + (j * 64 + srow) * 64 + sdst;
            __builtin_amdgcn_global_load_lds(
                (__attribute__((address_space(1))) void*)g,
                (__attribute__((address_space(3))) void*)d, 16, 0, 0);
        }
    };
    auto stageB = [&](int t_, int nh_, int buf_) {
        #pragma unroll
        for (int j = 0; j < 2; ++j) {
            const ushort_t* g = Bt + (size_t)(bn + (j * 2 + wr) * 64 + nh_ * 32
                                              + (w & 3) * 8 + (lane >> 3)) * K
                                   + t_ * 64 + scol;
            ushort_t* d = sB + buf_ * 16384 + nh_ * 8192 + (j * 64 + srow) * 64 + sdst;
            __builtin_amdgcn_global_load_lds(
                (__attribute__((address_space(1))) void*)g,
                (__attribute__((address_space(3))) void*)d, 16, 0, 0);
        }
    };

    // prologue: emulate stage cadence of virtual tiles -2,-1:
    // [Amh0(0), Bnh0(0), Amh1(0), Bnh1(0), Amh0(1), Bnh0(1)] = 12 load-instrs.
    stageA(0, 0, 0); stageB(0, 0, 0);
    stageA(0, 1, 0); stageB(0, 1, 0);
    stageA(1, 0, 1); stageB(1, 0, 1);
    asm volatile("s_waitcnt vmcnt(4)" ::: "memory");   // tile 0 fully landed

    for (int t2 = 0; t2 < NT; t2 += 2) {
        #pragma unroll
        for (int hIt = 0; hIt < 2; ++hIt) {
            const int t = t2 + hIt;
            const int cur = hIt;                 // t & 1
            const bool lastt = (t == NT - 1);
            #pragma unroll
            for (int q = 0; q < 4; ++q) {
                const int mh = q >> 1, nh = q & 1;
                if (q == 0) {
                    if (lastt) asm volatile("s_waitcnt vmcnt(0)" ::: "memory");
                    else       asm volatile("s_waitcnt vmcnt(8)" ::: "memory");
                } else if (q == 1 && !lastt) {
                    asm volatile("s_waitcnt vmcnt(6)" ::: "memory");
                }
                __builtin_amdgcn_s_barrier();

                bf16x8 af[4][2], bfr[2][2];
                #pragma unroll
                for (int tf = 0; tf < 4; ++tf)
                    #pragma unroll
                    for (int kk = 0; kk < 2; ++kk)
                        af[tf][kk] = *(const bf16x8*)&sA[cur * 16384 + mh * 8192
                                        + (wr * 64 + tf * 16 + l15) * 64 + ck[kk]];
                #pragma unroll
                for (int u = 0; u < 2; ++u)
                    #pragma unroll
                    for (int kk = 0; kk < 2; ++kk)
                        bfr[u][kk] = *(const bf16x8*)&sB[cur * 16384 + nh * 8192
                                        + (wcq * 32 + u * 16 + l15) * 64 + ck[kk]];

                // staging cadence (after barrier: W-A-R safe vs previous phase reads)
                if      (q == 0) { if (t + 1 < NT) stageA(t + 1, 1, cur ^ 1); }
                else if (q == 1) { if (t + 1 < NT) stageB(t + 1, 1, cur ^ 1); }
                else if (q == 2) { if (t + 2 < NT) stageA(t + 2, 0, cur); }
                else             { if (t + 2 < NT) stageB(t + 2, 0, cur); }

                __builtin_amdgcn_s_setprio(1);
                #pragma unroll
                for (int tf = 0; tf < 4; ++tf)
                    #pragma unroll
                    for (int u = 0; u < 2; ++u) {
                        acc[mh * 4 + tf][nh * 2 + u] =
                            __builtin_amdgcn_mfma_f32_16x16x32_bf16(
                                af[tf][0], bfr[u][0], acc[mh * 4 + tf][nh * 2 + u], 0, 0, 0);
                        acc[mh * 4 + tf][nh * 2 + u] =
                            __builtin_amdgcn_mfma_f32_16x16x32_bf16(
                                af[tf][1], bfr[u][1], acc[mh * 4 + tf][nh * 2 + u], 0, 0, 0);
                    }
                __builtin_amdgcn_s_setprio(0);
            }
        }
    }

    // epilogue: C/D layout col=lane&15, row=(lane>>4)*4+reg  [same verified convention]
    #pragma unroll
    for (int im = 0; im < 8; ++im) {
        const long row0 = bm + wr * 128 + (im >> 2) * 64 + (im & 3) * 16 + lg * 4;
        #pragma unroll
        for (int jn = 0; jn < 4; ++jn) {
            const long col = bn + wcq * 64 + jn * 16 + l15;
            const float bv = bias[col];
            #pragma unroll
            for (int r = 0; r < 4; ++r) {
                float v = gelu_f(acc[im][jn][r] + bv);
                if (OUT_BF16)
                    ((ushort_t*)C)[(size_t)(row0 + r) * N + col] = f2bf(v);
                else
                    ((float*)C)[(size_t)(row0 + r) * N + col] = v;
            }
        }
    }
}

// ---------------- segment sum: cell[b,t,:] = sum_{l: ids[b,l]==t} seq[b,l,:] ----------------
__global__ void segsum_kernel(const ushort_t* __restrict__ seq,   // [8*2048][1024] bf16
                              const int* __restrict__ ids,        // [8][2048]
                              ushort_t* __restrict__ cell)        // [8*256][1024] bf16
{
    const int b = blockIdx.x >> 8;
    const int t = blockIdx.x & 255;
    __shared__ int list[2048];
    __shared__ int count;
    if (threadIdx.x == 0) count = 0;
    __syncthreads();
    const int* idrow = ids + b * 2048;
    for (int l = threadIdx.x; l < 2048; l += 256) {
        if (idrow[l] == t) list[atomicAdd(&count, 1)] = l;
    }
    __syncthreads();
    const int n = count;
    float a0 = 0.f, a1 = 0.f, a2 = 0.f, a3 = 0.f;
    for (int i = 0; i < n; ++i) {
        const int l = list[i];
        const ushort4 v = *(const ushort4*)(seq + (size_t)(b * 2048 + l) * 1024 + threadIdx.x * 4);
        a0 += bf2f(v.x); a1 += bf2f(v.y); a2 += bf2f(v.z); a3 += bf2f(v.w);
    }
    ushort4* out = (ushort4*)(cell + (size_t)(b * 256 + t) * 1024);
    out[threadIdx.x] = make_ushort4(f2bf(a0), f2bf(a1), f2bf(a2), f2bf(a3));
}

// ---------------- gather: out[b,l,:] = cellout[b, ids[b,l], :] ----------------
__global__ void gather_kernel(const float4* __restrict__ cellout,  // [8*256][256] float4
                              const int* __restrict__ ids,
                              float4* __restrict__ out)            // [8*2048][256] float4
{
    const int tok = blockIdx.x;           // b*2048 + l
    const int b = tok >> 11;
    const int t = ids[tok];
    out[(size_t)tok * 256 + threadIdx.x] = cellout[(size_t)(b * 256 + t) * 256 + threadIdx.x];
}

extern "C" void kernel_launch(void* const* d_in, const int* in_sizes, int n_in,
                              void* d_out, int out_size, void* d_ws, size_t ws_size,
                              hipStream_t stream) {
    const float* former = (const float*)d_in[0];   // [8,2048,1024] f32
    const float* hidden = (const float*)d_in[1];   // [8,2048,1024] f32
    const int*   ids    = (const int*)d_in[2];     // [8,2048] i32
    // d_in[3] attention_mask: unused by reference
    const float* W_down = (const float*)d_in[4];   // [2048,1024] f32
    const float* b_down = (const float*)d_in[5];   // [1024] f32
    const float* W_row  = (const float*)d_in[6];   // [1024,1024] f32
    const float* b_row  = (const float*)d_in[7];   // [1024] f32
    float* out = (float*)d_out;                    // [8,2048,1024] f32

    char* ws = (char*)d_ws;
    ushort_t* Xb    = (ushort_t*)ws;  ws += (size_t)16384 * 2048 * 2;  // 64 MiB
    ushort_t* WdT   = (ushort_t*)ws;  ws += (size_t)1024 * 2048 * 2;   //  4 MiB
    ushort_t* WrT   = (ushort_t*)ws;  ws += (size_t)1024 * 1024 * 2;   //  2 MiB
    ushort_t* seq   = (ushort_t*)ws;  ws += (size_t)16384 * 1024 * 2;  // 32 MiB
    ushort_t* cellb = (ushort_t*)ws;  ws += (size_t)2048 * 1024 * 2;   //  4 MiB
    float*    cello = (float*)ws;                                      //  8 MiB

    static bool s_attr_set = false;
    if (!s_attr_set) {
        hipFuncSetAttribute(reinterpret_cast<const void*>(&gemm256_bias_gelu_kernel<true>),
                            hipFuncAttributeMaxDynamicSharedMemorySize, 131072);
        s_attr_set = true;
    }

    prep_kernel<<<19456, 256, 0, stream>>>((const float4*)former, (const float4*)hidden,
                                           (uint4*)Xb, W_down, WdT, W_row, WrT);

    // GEMM1: [16384 x 2048] @ [2048 x 1024] -> gelu -> bf16 seq  (256^2 pipelined)
    gemm256_bias_gelu_kernel<true><<<dim3(64, 4), 512, 131072, stream>>>(
        Xb, WdT, b_down, seq, 16384, 1024, 2048);

    segsum_kernel<<<2048, 256, 0, stream>>>(seq, ids, cellb);

    // GEMM2: [2048 x 1024] @ [1024 x 1024] -> gelu -> f32 cello  (128^2: 128 blocks)
    gemm_bias_gelu_kernel<false><<<dim3(16, 8), 256, 0, stream>>>(cellb, WrT, b_row, cello,
                                                                  2048, 1024, 1024);
    gather_kernel<<<16384, 256, 0, stream>>>((const float4*)cello, ids, (float4*)out);
}

// Round 2
// 321.384 us; speedup vs baseline: 1.0130x; 1.0130x over previous
//
#include <hip/hip_runtime.h>

typedef unsigned short ushort_t;
typedef __bf16 bf16x8 __attribute__((ext_vector_type(8)));
typedef float f32x4 __attribute__((ext_vector_type(4)));

__device__ __forceinline__ unsigned short f2bf(float f) {
    unsigned u = __float_as_uint(f);
    u += 0x7fffu + ((u >> 16) & 1u);
    return (unsigned short)(u >> 16);
}
__device__ __forceinline__ float bf2f(unsigned short h) {
    return __uint_as_float(((unsigned)h) << 16);
}
__device__ __forceinline__ float gelu_f(float x) {
    return 0.5f * x * (1.0f + erff(x * 0.70710678118654752440f));
}

// ---------------- prep: convert X -> bf16 AND transpose both weights ----------------
// blocks [0,16384): X rows; [16384,18432): W_down transpose; [18432,19456): W_row transpose
__global__ void prep_kernel(const float4* __restrict__ former,
                            const float4* __restrict__ hidden,
                            uint4* __restrict__ Xb4,
                            const float* __restrict__ Wd, ushort_t* __restrict__ WdT,
                            const float* __restrict__ Wr, ushort_t* __restrict__ WrT)
{
    const int blk = blockIdx.x;
    const int tid = threadIdx.x;
    if (blk < 16384) {
        const int row = blk;
        const float4* src = (tid < 128)
            ? (former + (size_t)row * 256 + (tid & 127) * 2)
            : (hidden + (size_t)row * 256 + (tid & 127) * 2);
        float4 a = src[0], b = src[1];
        uint4 o;
        o.x = f2bf(a.x) | ((unsigned)f2bf(a.y) << 16);
        o.y = f2bf(a.z) | ((unsigned)f2bf(a.w) << 16);
        o.z = f2bf(b.x) | ((unsigned)f2bf(b.y) << 16);
        o.w = f2bf(b.z) | ((unsigned)f2bf(b.w) << 16);
        Xb4[(size_t)row * 256 + tid] = o;
    } else {
        __shared__ float tile[32][33];
        const float* W; ushort_t* Wt; int R, C, b;
        if (blk < 16384 + 2048) { b = blk - 16384; W = Wd; Wt = WdT; R = 2048; C = 1024; }
        else                    { b = blk - 18432; W = Wr; Wt = WrT; R = 1024; C = 1024; }
        const int bx = (b & 31) * 32;
        const int by = (b >> 5) * 32;
        const int tx = tid & 31, ty = tid >> 5;
        #pragma unroll
        for (int j = 0; j < 32; j += 8)
            tile[ty + j][tx] = W[(size_t)(by + ty + j) * C + bx + tx];
        __syncthreads();
        #pragma unroll
        for (int j = 0; j < 32; j += 8)
            Wt[(size_t)(bx + ty + j) * R + by + tx] = f2bf(tile[tx][ty + j]);
    }
}

// ---------------- 128^2 m97-style GEMM (kept for GEMM2: small M, needs block count) ----
template <bool OUT_BF16>
__global__ void gemm_bias_gelu_kernel(const ushort_t* __restrict__ A,
                                      const ushort_t* __restrict__ Bt,
                                      const float* __restrict__ bias,
                                      void* __restrict__ C,
                                      int M, int N, int K)
{
    __shared__ __align__(16) ushort_t sA[128 * 64];
    __shared__ __align__(16) ushort_t sB[128 * 64];
    const int tid  = threadIdx.x;
    const int lane = tid & 63;
    const int wave = tid >> 6;
    const int wm = (wave & 1) * 64;
    const int wn = (wave >> 1) * 64;
    const long bm = (long)blockIdx.x * 128;
    const long bn = (long)blockIdx.y * 128;

    f32x4 acc[4][4] = {};

    const int srow = wave * 8 + (lane >> 3);
    const int scol = ((lane & 7) ^ (lane >> 3)) * 8;
    const int ldsbase = wave * 512;

    for (int k0 = 0; k0 < K; k0 += 64) {
        __syncthreads();
        #pragma unroll
        for (int it = 0; it < 4; ++it) {
            const ushort_t* gA = A + (size_t)(bm + it * 32 + srow) * K + k0 + scol;
            const ushort_t* gB = Bt + (size_t)(bn + it * 32 + srow) * K + k0 + scol;
            __builtin_amdgcn_global_load_lds(
                (__attribute__((address_space(1))) void*)gA,
                (__attribute__((address_space(3))) void*)&sA[ldsbase + it * 2048], 16, 0, 0);
            __builtin_amdgcn_global_load_lds(
                (__attribute__((address_space(1))) void*)gB,
                (__attribute__((address_space(3))) void*)&sB[ldsbase + it * 2048], 16, 0, 0);
        }
        __syncthreads();

        const int arow = wm + (lane & 15);
        const int brow = wn + (lane & 15);
        const int sw = lane & 7;
        const int cbase = lane >> 4;
        #pragma unroll
        for (int kk = 0; kk < 64; kk += 32) {
            const int koff = (((kk >> 3) + cbase) ^ sw) << 3;
            bf16x8 af[4], bfr[4];
            #pragma unroll
            for (int t = 0; t < 4; ++t) {
                af[t]  = *(const bf16x8*)&sA[(arow + t * 16) * 64 + koff];
                bfr[t] = *(const bf16x8*)&sB[(brow + t * 16) * 64 + koff];
            }
            #pragma unroll
            for (int i = 0; i < 4; ++i)
                #pragma unroll
                for (int j = 0; j < 4; ++j)
                    acc[i][j] = __builtin_amdgcn_mfma_f32_16x16x32_bf16(af[i], bfr[j], acc[i][j], 0, 0, 0);
        }
    }

    #pragma unroll
    for (int i = 0; i < 4; ++i) {
        const long row0 = bm + wm + i * 16 + (lane >> 4) * 4;
        #pragma unroll
        for (int j = 0; j < 4; ++j) {
            const long col = bn + wn + j * 16 + (lane & 15);
            const float bv = bias[col];
            #pragma unroll
            for (int r = 0; r < 4; ++r) {
                float v = gelu_f(acc[i][j][r] + bv);
                if (OUT_BF16)
                    ((ushort_t*)C)[(size_t)(row0 + r) * N + col] = f2bf(v);
                else
                    ((float*)C)[(size_t)(row0 + r) * N + col] = v;
            }
        }
    }
}

// ---------------- 256^2 8-wave deep-pipelined GEMM (GEMM1) --------------------------
// v2: cross-phase REGISTER REUSE of LDS subtiles (24 ds_read_b128 per K-tile per wave,
// was 48). Staging cadence / vmcnt ledger / swizzle identical to v1 (verified).
//
// Per tile t (cur = t&1), phases and subtile liveness:
//   q0: read af=A[cur][mh0](8) b0=B[cur][nh0](4); stage A(t+1,mh1,cur^1); mfma(af,b0)
//   q1: read b1=B[cur][nh1](4);  reuse af;        stage B(t+1,nh1,cur^1); mfma(af,b1)
//   q2: read af=A[cur][mh1](8);  reuse b0;        stage A(t+2,mh0,cur);   mfma(af,b0)
//   q3: no reads;                reuse af,b1;     stage B(t+2,nh0,cur);   mfma(af,b1)
// Ledger (2 load-instrs per stage): q0 needs A-mh0(t),B-nh0(t) staged at t-2 q2/q3,
// 8 younger loads -> vmcnt(8). q1 needs B-nh1(t) (t-1 q1), 6 younger -> vmcnt(6).
// q2 needs A-mh1(t) (t-1 q0) which is OLDER than B-nh1(t) -> covered by q1's wait.
// W-A-R: every staged slot's last LDS read is >=2 barriers before the stage.
template <bool OUT_BF16>
__global__ __launch_bounds__(512, 2)
void gemm256_bias_gelu_kernel(const ushort_t* __restrict__ A,
                              const ushort_t* __restrict__ Bt,
                              const float* __restrict__ bias,
                              void* __restrict__ C,
                              int M, int N, int K)
{
    extern __shared__ float4 smem4[];
    ushort_t* sA = (ushort_t*)smem4;   // 2 buf x 2 mh x 128 x 64 bf16 (64 KiB)
    ushort_t* sB = sA + 32768;         // 64 KiB

    const int tid  = threadIdx.x;
    const int lane = tid & 63;
    const int w    = tid >> 6;          // 0..7
    const int wr   = w >> 2;            // 0..1  A row-block of this wave
    const int wcq  = w & 3;             // 0..3  B col-block of this wave
    const long bm = (long)blockIdx.x * 256;
    const long bn = (long)blockIdx.y * 256;
    const int NT = K >> 6;              // K-tiles of 64 (even; GEMM1: 32)

    const int srow = w * 8 + (lane >> 3);             // 0..63
    const int scol = ((lane & 7) ^ (lane >> 3)) * 8;  // swizzled global k-chunk (elems)
    const int sdst = (lane & 7) * 8;                  // lds chunk (elems)

    const int l15 = lane & 15;
    const int lg  = lane >> 4;
    const int sw  = lane & 7;
    const int ck[2] = { ((0 + lg) ^ sw) * 8, ((4 + lg) ^ sw) * 8 };

    f32x4 acc[8][4] = {};

    auto stageA = [&](int t_, int mh_, int buf_) {
        #pragma unroll
        for (int j = 0; j < 2; ++j) {
            const ushort_t* g = A + (size_t)(bm + j * 128 + mh_ * 64 + srow) * K
                                  + t_ * 64 + scol;
            ushort_t* d = sA + buf_ * 16384 + mh_ * 8192 + (j * 64 + srow) * 64 + sdst;
            __builtin_amdgcn_global_load_lds(
                (__attribute__((address_space(1))) void*)g,
                (__attribute__((address_space(3))) void*)d, 16, 0, 0);
        }
    };
    auto stageB = [&](int t_, int nh_, int buf_) {
        #pragma unroll
        for (int j = 0; j < 2; ++j) {
            const ushort_t* g = Bt + (size_t)(bn + (j * 2 + wr) * 64 + nh_ * 32
                                              + (w & 3) * 8 + (lane >> 3)) * K
                                   + t_ * 64 + scol;
            ushort_t* d = sB + buf_ * 16384 + nh_ * 8192 + (j * 64 + srow) * 64 + sdst;
            __builtin_amdgcn_global_load_lds(
                (__attribute__((address_space(1))) void*)g,
                (__attribute__((address_space(3))) void*)d, 16, 0, 0);
        }
    };

    bf16x8 af[4][2];   // current A quadrant (reused across two phases)
    bf16x8 b0[2][2];   // B nh0 (live q0..q2)
    bf16x8 b1[2][2];   // B nh1 (live q1..q3)

    auto readA = [&](int mh_, int buf_) {
        #pragma unroll
        for (int tf = 0; tf < 4; ++tf)
            #pragma unroll
            for (int kk = 0; kk < 2; ++kk)
                af[tf][kk] = *(const bf16x8*)&sA[buf_ * 16384 + mh_ * 8192
                                + (wr * 64 + tf * 16 + l15) * 64 + ck[kk]];
    };
    auto readB = [&](bf16x8 (&dst)[2][2], int nh_, int buf_) {
        #pragma unroll
        for (int u = 0; u < 2; ++u)
            #pragma unroll
            for (int kk = 0; kk < 2; ++kk)
                dst[u][kk] = *(const bf16x8*)&sB[buf_ * 16384 + nh_ * 8192
                                + (wcq * 32 + u * 16 + l15) * 64 + ck[kk]];
    };
    auto mfma16 = [&](bf16x8 (&bf_)[2][2], int mh_, int nh_) {
        __builtin_amdgcn_s_setprio(1);
        #pragma unroll
        for (int tf = 0; tf < 4; ++tf)
            #pragma unroll
            for (int u = 0; u < 2; ++u) {
                acc[mh_ * 4 + tf][nh_ * 2 + u] =
                    __builtin_amdgcn_mfma_f32_16x16x32_bf16(
                        af[tf][0], bf_[u][0], acc[mh_ * 4 + tf][nh_ * 2 + u], 0, 0, 0);
                acc[mh_ * 4 + tf][nh_ * 2 + u] =
                    __builtin_amdgcn_mfma_f32_16x16x32_bf16(
                        af[tf][1], bf_[u][1], acc[mh_ * 4 + tf][nh_ * 2 + u], 0, 0, 0);
            }
        __builtin_amdgcn_s_setprio(0);
    };

    // prologue: [Amh0(0), Bnh0(0), Amh1(0), Bnh1(0), Amh0(1), Bnh0(1)] = 12 loads
    stageA(0, 0, 0); stageB(0, 0, 0);
    stageA(0, 1, 0); stageB(0, 1, 0);
    stageA(1, 0, 1); stageB(1, 0, 1);
    asm volatile("s_waitcnt vmcnt(4)" ::: "memory");   // tile 0 fully landed

    for (int t2 = 0; t2 < NT; t2 += 2) {
        #pragma unroll
        for (int hIt = 0; hIt < 2; ++hIt) {
            const int t = t2 + hIt;
            const int cur = hIt;                 // t & 1
            const bool lastt = (t == NT - 1);

            // ---- q0: quad (mh0, nh0)
            if (lastt) asm volatile("s_waitcnt vmcnt(0)" ::: "memory");
            else       asm volatile("s_waitcnt vmcnt(8)" ::: "memory");
            __builtin_amdgcn_s_barrier();
            if (t + 1 < NT) stageA(t + 1, 1, cur ^ 1);
            readA(0, cur);
            readB(b0, 0, cur);
            mfma16(b0, 0, 0);

            // ---- q1: quad (mh0, nh1) — reuse af
            if (!lastt) asm volatile("s_waitcnt vmcnt(6)" ::: "memory");
            __builtin_amdgcn_s_barrier();
            if (t + 1 < NT) stageB(t + 1, 1, cur ^ 1);
            readB(b1, 1, cur);
            mfma16(b1, 0, 1);

            // ---- q2: quad (mh1, nh0) — reuse b0, A-mh1(t) covered by q1's vmcnt
            __builtin_amdgcn_s_barrier();
            if (t + 2 < NT) stageA(t + 2, 0, cur);
            readA(1, cur);
            mfma16(b0, 1, 0);

            // ---- q3: quad (mh1, nh1) — zero LDS reads
            __builtin_amdgcn_s_barrier();
            if (t + 2 < NT) stageB(t + 2, 0, cur);
            mfma16(b1, 1, 1);
        }
    }

    // epilogue: C/D layout col=lane&15, row=(lane>>4)*4+reg  [verified convention]
    #pragma unroll
    for (int im = 0; im < 8; ++im) {
        const long row0 = bm + wr * 128 + (im >> 2) * 64 + (im & 3) * 16 + lg * 4;
        #pragma unroll
        for (int jn = 0; jn < 4; ++jn) {
            const long col = bn + wcq * 64 + jn * 16 + l15;
            const float bv = bias[col];
            #pragma unroll
            for (int r = 0; r < 4; ++r) {
                float v = gelu_f(acc[im][jn][r] + bv);
                if (OUT_BF16)
                    ((ushort_t*)C)[(size_t)(row0 + r) * N + col] = f2bf(v);
                else
                    ((float*)C)[(size_t)(row0 + r) * N + col] = v;
            }
        }
    }
}

// ---------------- segment sum: cell[b,t,:] = sum_{l: ids[b,l]==t} seq[b,l,:] ----------------
__global__ void segsum_kernel(const ushort_t* __restrict__ seq,   // [8*2048][1024] bf16
                              const int* __restrict__ ids,        // [8][2048]
                              ushort_t* __restrict__ cell)        // [8*256][1024] bf16
{
    const int b = blockIdx.x >> 8;
    const int t = blockIdx.x & 255;
    __shared__ int list[2048];
    __shared__ int count;
    if (threadIdx.x == 0) count = 0;
    __syncthreads();
    const int* idrow = ids + b * 2048;
    for (int l = threadIdx.x; l < 2048; l += 256) {
        if (idrow[l] == t) list[atomicAdd(&count, 1)] = l;
    }
    __syncthreads();
    const int n = count;
    float a0 = 0.f, a1 = 0.f, a2 = 0.f, a3 = 0.f;
    for (int i = 0; i < n; ++i) {
        const int l = list[i];
        const ushort4 v = *(const ushort4*)(seq + (size_t)(b * 2048 + l) * 1024 + threadIdx.x * 4);
        a0 += bf2f(v.x); a1 += bf2f(v.y); a2 += bf2f(v.z); a3 += bf2f(v.w);
    }
    ushort4* out = (ushort4*)(cell + (size_t)(b * 256 + t) * 1024);
    out[threadIdx.x] = make_ushort4(f2bf(a0), f2bf(a1), f2bf(a2), f2bf(a3));
}

// ---------------- gather: out[b,l,:] = cellout[b, ids[b,l], :] ----------------
__global__ void gather_kernel(const float4* __restrict__ cellout,  // [8*256][256] float4
                              const int* __restrict__ ids,
                              float4* __restrict__ out)            // [8*2048][256] float4
{
    const int tok = blockIdx.x;           // b*2048 + l
    const int b = tok >> 11;
    const int t = ids[tok];
    out[(size_t)tok * 256 + threadIdx.x] = cellout[(size_t)(b * 256 + t) * 256 + threadIdx.x];
}

extern "C" void kernel_launch(void* const* d_in, const int* in_sizes, int n_in,
                              void* d_out, int out_size, void* d_ws, size_t ws_size,
                              hipStream_t stream) {
    const float* former = (const float*)d_in[0];   // [8,2048,1024] f32
    const float* hidden = (const float*)d_in[1];   // [8,2048,1024] f32
    const int*   ids    = (const int*)d_in[2];     // [8,2048] i32
    // d_in[3] attention_mask: unused by reference
    const float* W_down = (const float*)d_in[4];   // [2048,1024] f32
    const float* b_down = (const float*)d_in[5];   // [1024] f32
    const float* W_row  = (const float*)d_in[6];   // [1024,1024] f32
    const float* b_row  = (const float*)d_in[7];   // [1024] f32
    float* out = (float*)d_out;                    // [8,2048,1024] f32

    char* ws = (char*)d_ws;
    ushort_t* Xb    = (ushort_t*)ws;  ws += (size_t)16384 * 2048 * 2;  // 64 MiB
    ushort_t* WdT   = (ushort_t*)ws;  ws += (size_t)1024 * 2048 * 2;   //  4 MiB
    ushort_t* WrT   = (ushort_t*)ws;  ws += (size_t)1024 * 1024 * 2;   //  2 MiB
    ushort_t* seq   = (ushort_t*)ws;  ws += (size_t)16384 * 1024 * 2;  // 32 MiB
    ushort_t* cellb = (ushort_t*)ws;  ws += (size_t)2048 * 1024 * 2;   //  4 MiB
    float*    cello = (float*)ws;                                      //  8 MiB

    static bool s_attr_set = false;
    if (!s_attr_set) {
        hipFuncSetAttribute(reinterpret_cast<const void*>(&gemm256_bias_gelu_kernel<true>),
                            hipFuncAttributeMaxDynamicSharedMemorySize, 131072);
        s_attr_set = true;
    }

    prep_kernel<<<19456, 256, 0, stream>>>((const float4*)former, (const float4*)hidden,
                                           (uint4*)Xb, W_down, WdT, W_row, WrT);

    // GEMM1: [16384 x 2048] @ [2048 x 1024] -> gelu -> bf16 seq  (256^2 pipelined)
    gemm256_bias_gelu_kernel<true><<<dim3(64, 4), 512, 131072, stream>>>(
        Xb, WdT, b_down, seq, 16384, 1024, 2048);

    segsum_kernel<<<2048, 256, 0, stream>>>(seq, ids, cellb);

    // GEMM2: [2048 x 1024] @ [1024 x 1024] -> gelu -> f32 cello  (128^2: 128 blocks)
    gemm_bias_gelu_kernel<false><<<dim3(16, 8), 256, 0, stream>>>(cellb, WrT, b_row, cello,
                                                                  2048, 1024, 1024);
    gather_kernel<<<16384, 256, 0, stream>>>((const float4*)cello, ids, (float4*)out);
}